// Round 4
// baseline (339.942 us; speedup 1.0000x reference)
//
#include <hip/hip_runtime.h>
#include <hip/hip_bf16.h>
#include <cstdint>
#include <cstddef>

// Problem constants
#define B_  8192
#define D_  256
#define H_  512
#define K_  1280   // D + 2H
#define N_  2560   // 5H
#define NT_ 320    // N-tile: 2 h-groups of (32 h x 5 gates)
#define BM_ 256    // M-tile
#define BK_ 64     // K-step

typedef short short8  __attribute__((ext_vector_type(8)));
typedef float f32x4   __attribute__((ext_vector_type(4)));
typedef float f32x16  __attribute__((ext_vector_type(16)));

__device__ __forceinline__ float sigf(float x)     { return 1.f / (1.f + __expf(-x)); }
__device__ __forceinline__ float tanhfast(float x) { return 1.f - 2.f / (__expf(2.f * x) + 1.f); }

// ---------------------------------------------------------------------------
// prep kernels (unchanged).
// ---------------------------------------------------------------------------
struct WPtrs {
    const float* U[5];
    const float* Wt[5];
    const float* Ws[5];
};

__global__ void prep_a_kernel(const float* __restrict__ x, const float* __restrict__ ht,
                              const float* __restrict__ hs, __hip_bfloat16* __restrict__ A) {
    int t = blockIdx.x * 256 + threadIdx.x;   // over B_*K_/8
    int idx8 = t * 8;
    int b = idx8 / K_;
    int k = idx8 - b * K_;
    const float* src;
    if (k < D_)            src = x  + (size_t)b * D_ + k;
    else if (k < D_ + H_)  src = ht + (size_t)b * H_ + (k - D_);
    else                   src = hs + (size_t)b * H_ + (k - D_ - H_);
    f32x4 v0 = *(const f32x4*)(src);
    f32x4 v1 = *(const f32x4*)(src + 4);
    union { short8 s; __hip_bfloat16 h[8]; } o;
    o.h[0] = __float2bfloat16(v0[0]); o.h[1] = __float2bfloat16(v0[1]);
    o.h[2] = __float2bfloat16(v0[2]); o.h[3] = __float2bfloat16(v0[3]);
    o.h[4] = __float2bfloat16(v1[0]); o.h[5] = __float2bfloat16(v1[1]);
    o.h[6] = __float2bfloat16(v1[2]); o.h[7] = __float2bfloat16(v1[3]);
    *(short8*)(A + idx8) = o.s;
}

__global__ void prep_w_kernel(WPtrs p, __hip_bfloat16* __restrict__ WT) {
    __shared__ __hip_bfloat16 tile[64][66];   // 66-pitch: 2-way (free) on read
    int bid2 = blockIdx.x;                 // hblk + 8*(kblk + 20*g)
    int hblk = bid2 & 7;
    int kblk = (bid2 >> 3) % 20;
    int g    = bid2 / 160;
    int k0 = kblk * 64;
    int h0 = hblk * 64;
    const float* src; int kl0;
    if (k0 < 256)      { src = p.U[g];  kl0 = k0; }
    else if (k0 < 768) { src = p.Wt[g]; kl0 = k0 - 256; }
    else               { src = p.Ws[g]; kl0 = k0 - 768; }
    int tid = threadIdx.x;
    int tk = tid >> 6;    // 0..3
    int th = tid & 63;
    for (int r = 0; r < 16; ++r) {
        int kl = r * 4 + tk;
        tile[kl][th] = __float2bfloat16(src[(size_t)(kl0 + kl) * H_ + h0 + th]);
    }
    __syncthreads();
    for (int r = 0; r < 16; ++r) {
        int hl = r * 4 + tk;           // h within tile
        int h  = h0 + hl;
        int np = (h >> 5) * 160 + g * 32 + (h & 31);
        WT[(size_t)np * K_ + k0 + th] = tile[th][hl];
    }
}

// ---------------------------------------------------------------------------
// Fused GEMM + LSTM epilogue — 4-wave, 4x5-frag register tile.
//
// R3 post-mortem arithmetic: MFMA floor = 6400 instr/CU x 8.07 cyc = 21.5 us;
// measured 89 us at MfmaUtil 24% (= exactly floor/dur). The invariant across
// all prior rounds was the 2x5 register tile: 0.7 b128 LDS reads per MFMA.
// This round halves operand traffic per MFMA: wave tile 128m x 160n =
// 4 m-frags x 5 n-frags (reads/MFMA = 9/20 = 0.45), acc = 320 AGPRs.
// 4 waves/block, 256 thr, 1 block/CU (grid 256), BK=64 dbuf (144 KB LDS).
// No inline-asm waits: compiler's counted lgkmcnt + ks-pipelining (m97) beats
// a hard lgkmcnt(0)+sched_barrier fence.
// Grid is m-fast: the 8 blocks sharing an A m-tile land on one XCD round ->
// A read ~once from L3; WT (6.25 MB) streams per-XCD.
// ---------------------------------------------------------------------------
#define GLD16(gp, lp)                                                              \
    __builtin_amdgcn_global_load_lds(                                              \
        (const __attribute__((address_space(1))) unsigned int*)(gp),               \
        (__attribute__((address_space(3))) unsigned int*)(lp), 16, 0, 0)

__global__ __launch_bounds__(256, 1) void gemm_fused_kernel(
    const __hip_bfloat16* __restrict__ A, const __hip_bfloat16* __restrict__ WT,
    const float* __restrict__ ct, const float* __restrict__ cs,
    const float* __restrict__ bi, const float* __restrict__ bfs,
    const float* __restrict__ bft, const float* __restrict__ bo,
    const float* __restrict__ bc, float* __restrict__ out) {
    __shared__ alignas(16) unsigned short sA[2][BM_ * BK_];  // 64 KB
    __shared__ alignas(16) unsigned short sB[2][NT_ * BK_];  // 80 KB

    int tid = threadIdx.x;
    int m0 = blockIdx.x * BM_;   // m-fast: A-tile shared by concurrent XCD-mates
    int n0 = blockIdx.y * NT_;
    int wid  = tid >> 6, lane = tid & 63;
    int wm   = wid >> 1;         // 0..1: 128-row slice
    int wn   = wid & 1;          // 0..1: 160-col (32-h-group x 5 gates) slice
    int half = lane >> 5, l31 = lane & 31;

    int hg = blockIdx.y * 2 + wn;      // 32-h group
    int h  = hg * 32 + l31;            // this lane's h column
    float Bi = bi[h], Bfs = bfs[h], Bft = bft[h], Bo = bo[h], Bc = bc[h];

    f32x16 acc[4][5];
#pragma unroll
    for (int i = 0; i < 4; ++i)
#pragma unroll
        for (int j = 0; j < 5; ++j)
            acc[i][j] = (f32x16)(0.f);

    // ---- staging: rows of BK=64 shorts = 8 chunks of 16B.
    // Thread tid, round i: LDS chunk c = tid + 256*i -> row = c>>3 (= (tid>>3)+32i),
    // LDS pos = tid&7. Global k-chunk = (tid&7) ^ ((row>>1)&3); since 32i is
    // divisible by 4 in (row>>1)&3, the swizzle is i-independent.
    int r0  = tid >> 3;                                  // 0..31
    int kcS = ((tid & 7) ^ ((r0 >> 1) & 3)) * 8;         // shorts offset in row
    const __hip_bfloat16* aBase = A  + (size_t)(m0 + r0) * K_ + kcS;
    const __hip_bfloat16* bBase = WT + (size_t)(n0 + r0) * K_ + kcS;
    int t8 = tid * 8;                                    // LDS dst (linear, 16B/thr)

#define STAGE(bufsel, koff)                                                       \
    do {                                                                          \
        _Pragma("unroll")                                                         \
        for (int i_ = 0; i_ < 8; ++i_)                                            \
            GLD16(aBase + (size_t)i_ * 32 * K_ + (koff), sA[bufsel] + i_ * 2048 + t8); \
        _Pragma("unroll")                                                         \
        for (int i_ = 0; i_ < 10; ++i_)                                           \
            GLD16(bBase + (size_t)i_ * 32 * K_ + (koff), sB[bufsel] + i_ * 2048 + t8); \
    } while (0)

    // ---- fragment read offsets: addr(shorts) = row*64 + pos*8,
    // pos = (ks*2+half) ^ ((row>>1)&3). Content check: LDS[row][pos] holds
    // global chunk pos^swz(row), so reading pos = g^swz yields chunk g. ----
    int arow[4], brow[5], aswz[4], bswz[5];
#pragma unroll
    for (int i = 0; i < 4; ++i) {
        arow[i] = (wm * 128 + i * 32 + l31);
        aswz[i] = (arow[i] >> 1) & 3;
    }
#pragma unroll
    for (int j = 0; j < 5; ++j) {
        brow[j] = (wn * 160 + j * 32 + l31);
        bswz[j] = (brow[j] >> 1) & 3;
    }

    // ---- prologue ----
    STAGE(0, 0);
    __syncthreads();

    const int nt = K_ / BK_;   // 20
    for (int t = 0; t < nt; ++t) {
        int cur = t & 1;
        if (t + 1 < nt) STAGE(cur ^ 1, (size_t)(t + 1) * BK_);  // fly all step
        const unsigned short* sAc = sA[cur];
        const unsigned short* sBc = sB[cur];
#pragma unroll
        for (int ks = 0; ks < 4; ++ks) {
            short8 a[4], b[5];
            int g = ks * 2 + half;
#pragma unroll
            for (int i = 0; i < 4; ++i)
                a[i] = *(const short8*)(sAc + arow[i] * 64 + (g ^ aswz[i]) * 8);
#pragma unroll
            for (int j = 0; j < 5; ++j)
                b[j] = *(const short8*)(sBc + brow[j] * 64 + (g ^ bswz[j]) * 8);
            __builtin_amdgcn_s_setprio(1);
#pragma unroll
            for (int j = 0; j < 5; ++j)
#pragma unroll
                for (int i = 0; i < 4; ++i)
                    acc[i][j] = __builtin_amdgcn_mfma_f32_32x32x16_bf16(a[i], b[j], acc[i][j], 0, 0, 0);
            __builtin_amdgcn_s_setprio(0);
        }
        __syncthreads();   // vmcnt drain: loads had the whole 80-MFMA step
    }
#undef STAGE

    // ---- lane-local LSTM epilogue ----
    // 32x32 C/D layout: col = lane&31 (h), row = (r&3) + 8*(r>>2) + 4*half.
#pragma unroll
    for (int i = 0; i < 4; ++i) {
        int rbase = m0 + wm * 128 + i * 32 + 4 * half;
#pragma unroll
        for (int r = 0; r < 16; ++r) {
            int row = rbase + (r & 3) + 8 * (r >> 2);
            size_t idx = (size_t)row * H_ + h;
            float i_n  = sigf(acc[i][0][r] + Bi);
            float fs_n = sigf(acc[i][1][r] + Bfs);
            float ft_n = sigf(acc[i][2][r] + Bft);
            float o_n  = sigf(acc[i][3][r] + Bo);
            float c_n  = tanhfast(acc[i][4][r] + Bc);
            float ch   = i_n * c_n + ft_n * ct[idx] + fs_n * cs[idx];
            out[idx] = o_n * tanhfast(ch);
            out[(size_t)B_ * H_ + idx] = ch;
        }
    }
}

// ---------------------------------------------------------------------------
// Fallback (ws too small): one block per row, fp32 direct. Slow but correct.
// ---------------------------------------------------------------------------
struct AllW {
    const float* U[5];
    const float* Wt[5];
    const float* Ws[5];
    const float* bias[5];
};

__global__ __launch_bounds__(512) void fallback_kernel(const float* __restrict__ x,
                                                       const float* __restrict__ ht,
                                                       const float* __restrict__ hs,
                                                       const float* __restrict__ ct,
                                                       const float* __restrict__ cs,
                                                       AllW w, float* __restrict__ out) {
    __shared__ float arow[K_];
    int b = blockIdx.x;
    int h = threadIdx.x;
    for (int k = h; k < K_; k += 512) {
        float v;
        if (k < D_)           v = x[b * D_ + k];
        else if (k < D_ + H_) v = ht[b * H_ + k - D_];
        else                  v = hs[b * H_ + k - D_ - H_];
        arow[k] = v;
    }
    __syncthreads();
    float g[5];
    for (int gi = 0; gi < 5; ++gi) {
        float s = w.bias[gi][h];
        const float* U = w.U[gi];
        for (int k = 0; k < D_; ++k) s += arow[k] * U[(size_t)k * H_ + h];
        const float* Wt = w.Wt[gi];
        for (int k = 0; k < H_; ++k) s += arow[D_ + k] * Wt[(size_t)k * H_ + h];
        const float* Ws = w.Ws[gi];
        for (int k = 0; k < H_; ++k) s += arow[D_ + H_ + k] * Ws[(size_t)k * H_ + h];
        g[gi] = s;
    }
    int idx = b * H_ + h;
    float i_n = sigf(g[0]), fs_n = sigf(g[1]), ft_n = sigf(g[2]), o_n = sigf(g[3]);
    float c_n = tanhfast(g[4]);
    float ch  = i_n * c_n + ft_n * ct[idx] + fs_n * cs[idx];
    out[idx] = o_n * tanhfast(ch);
    out[(size_t)B_ * H_ + idx] = ch;
}

// ---------------------------------------------------------------------------
extern "C" void kernel_launch(void* const* d_in, const int* in_sizes, int n_in,
                              void* d_out, int out_size, void* d_ws, size_t ws_size,
                              hipStream_t stream) {
    const float* x  = (const float*)d_in[0];
    const float* ht = (const float*)d_in[1];
    const float* hs = (const float*)d_in[2];
    const float* ct = (const float*)d_in[3];
    const float* cs = (const float*)d_in[4];

    WPtrs wp;
    AllW  aw;
    const float* bias[5];
    for (int g = 0; g < 5; ++g) {
        wp.U[g]  = (const float*)d_in[5 + g * 4 + 0];
        wp.Wt[g] = (const float*)d_in[5 + g * 4 + 1];
        wp.Ws[g] = (const float*)d_in[5 + g * 4 + 2];
        bias[g]  = (const float*)d_in[5 + g * 4 + 3];
        aw.U[g] = wp.U[g]; aw.Wt[g] = wp.Wt[g]; aw.Ws[g] = wp.Ws[g]; aw.bias[g] = bias[g];
    }
    float* out = (float*)d_out;

    size_t szA = (size_t)B_ * K_ * 2;  // 20 MB
    size_t szW = (size_t)N_ * K_ * 2;  // 6.25 MB

    if (ws_size >= szA + szW) {
        __hip_bfloat16* Abf = (__hip_bfloat16*)d_ws;
        __hip_bfloat16* WT  = (__hip_bfloat16*)((char*)d_ws + szA);

        prep_a_kernel<<<5120, 256, 0, stream>>>(x, ht, hs, Abf);
        prep_w_kernel<<<800, 256, 0, stream>>>(wp, WT);
        gemm_fused_kernel<<<dim3(B_ / BM_, N_ / NT_), 256, 0, stream>>>(
            Abf, WT, ct, cs, bias[0], bias[1], bias[2], bias[3], bias[4], out);
    } else {
        fallback_kernel<<<B_, 512, 0, stream>>>(x, ht, hs, ct, cs, aw, out);
    }
}

// Round 5
// 241.317 us; speedup vs baseline: 1.4087x; 1.4087x over previous
//
#include <hip/hip_runtime.h>
#include <hip/hip_bf16.h>
#include <cstdint>
#include <cstddef>

// Problem constants
#define B_  8192
#define D_  256
#define H_  512
#define K_  1280   // D + 2H
#define N_  2560   // 5H
#define NT_ 320    // N-tile: 2 h-groups of (32 h x 5 gates)
#define BM_ 256    // M-tile
#define BK_ 64     // K-step

typedef short short8  __attribute__((ext_vector_type(8)));
typedef float f32x4   __attribute__((ext_vector_type(4)));
typedef float f32x16  __attribute__((ext_vector_type(16)));

__device__ __forceinline__ float sigf(float x)     { return 1.f / (1.f + __expf(-x)); }
__device__ __forceinline__ float tanhfast(float x) { return 1.f - 2.f / (__expf(2.f * x) + 1.f); }

// ---------------------------------------------------------------------------
// prep kernels (unchanged from R3).
// ---------------------------------------------------------------------------
struct WPtrs {
    const float* U[5];
    const float* Wt[5];
    const float* Ws[5];
};

__global__ void prep_a_kernel(const float* __restrict__ x, const float* __restrict__ ht,
                              const float* __restrict__ hs, __hip_bfloat16* __restrict__ A) {
    int t = blockIdx.x * 256 + threadIdx.x;   // over B_*K_/8
    int idx8 = t * 8;
    int b = idx8 / K_;
    int k = idx8 - b * K_;
    const float* src;
    if (k < D_)            src = x  + (size_t)b * D_ + k;
    else if (k < D_ + H_)  src = ht + (size_t)b * H_ + (k - D_);
    else                   src = hs + (size_t)b * H_ + (k - D_ - H_);
    f32x4 v0 = *(const f32x4*)(src);
    f32x4 v1 = *(const f32x4*)(src + 4);
    union { short8 s; __hip_bfloat16 h[8]; } o;
    o.h[0] = __float2bfloat16(v0[0]); o.h[1] = __float2bfloat16(v0[1]);
    o.h[2] = __float2bfloat16(v0[2]); o.h[3] = __float2bfloat16(v0[3]);
    o.h[4] = __float2bfloat16(v1[0]); o.h[5] = __float2bfloat16(v1[1]);
    o.h[6] = __float2bfloat16(v1[2]); o.h[7] = __float2bfloat16(v1[3]);
    *(short8*)(A + idx8) = o.s;
}

__global__ void prep_w_kernel(WPtrs p, __hip_bfloat16* __restrict__ WT) {
    __shared__ __hip_bfloat16 tile[64][66];   // 66-pitch: 2-way (free) on read
    int bid2 = blockIdx.x;                 // hblk + 8*(kblk + 20*g)
    int hblk = bid2 & 7;
    int kblk = (bid2 >> 3) % 20;
    int g    = bid2 / 160;
    int k0 = kblk * 64;
    int h0 = hblk * 64;
    const float* src; int kl0;
    if (k0 < 256)      { src = p.U[g];  kl0 = k0; }
    else if (k0 < 768) { src = p.Wt[g]; kl0 = k0 - 256; }
    else               { src = p.Ws[g]; kl0 = k0 - 768; }
    int tid = threadIdx.x;
    int tk = tid >> 6;    // 0..3
    int th = tid & 63;
    for (int r = 0; r < 16; ++r) {
        int kl = r * 4 + tk;
        tile[kl][th] = __float2bfloat16(src[(size_t)(kl0 + kl) * H_ + h0 + th]);
    }
    __syncthreads();
    for (int r = 0; r < 16; ++r) {
        int hl = r * 4 + tk;           // h within tile
        int h  = h0 + hl;
        int np = (h >> 5) * 160 + g * 32 + (h & 31);
        WT[(size_t)np * K_ + k0 + th] = tile[th][hl];
    }
}

// ---------------------------------------------------------------------------
// Fused GEMM + LSTM epilogue — m201-style 4-phase schedule on R3 geometry.
//
// R4 post-mortem: 4x5 acc (320 regs) spilled (VGPR 256, WRITE +29MB) ->
// revert to 8 waves x (2m x 5n) frags, BM=256, NT=320, BK=64, dbuf 144KB.
// R0-R3 all pinned at ~600 TF = m233's measured "2-phase stall" regime.
// This round ports the verified 8-phase elements:
//   - RAW s_barrier (no compiler vmcnt(0) drain per barrier)
//   - 4 phases per K-step (one ks-slice each): {stage-issue + 7 ds_read ->
//     bar -> lgkmcnt(0) -> setprio(1) 10 MFMA setprio(0) -> bar}
//   - ONE vmcnt(0) per K-step (end of ph3), waiting loads issued 1-3 phases
//     earlier (A in ph0: ~3-phase lead for HBM; B in ph1/2: L2-hit on the
//     XCD-pinned n-tile)
//   - full 3-bit XOR swizzle pos = g ^ (row&7): spreads the 8 pos-slots over
//     all 32 banks (the old 2-bit swizzle left 8 lanes per 4-bank group ->
//     the flat +4 cyc/read conflict count seen in R0-R3)
// Safety: every wave executes lgkmcnt(0) (own reads done) before the phase's
// final barrier, so next phase's staging can never overwrite LDS words that
// some wave still has in flight.
// ---------------------------------------------------------------------------
#define GLD16(gp, lp)                                                              \
    __builtin_amdgcn_global_load_lds(                                              \
        (const __attribute__((address_space(1))) unsigned int*)(gp),               \
        (__attribute__((address_space(3))) unsigned int*)(lp), 16, 0, 0)

__global__ __launch_bounds__(512, 2) void gemm_fused_kernel(
    const __hip_bfloat16* __restrict__ A, const __hip_bfloat16* __restrict__ WT,
    const float* __restrict__ ct, const float* __restrict__ cs,
    const float* __restrict__ bi, const float* __restrict__ bfs,
    const float* __restrict__ bft, const float* __restrict__ bo,
    const float* __restrict__ bc, float* __restrict__ out) {
    __shared__ alignas(16) unsigned short sA[2][BM_ * BK_];  // 64 KB
    __shared__ alignas(16) unsigned short sB[2][NT_ * BK_];  // 80 KB

    int tid = threadIdx.x;
    int n0 = blockIdx.x * NT_;   // x = n: each XCD owns one n-tile -> WT L2-hot
    int m0 = blockIdx.y * BM_;
    int wid  = tid >> 6, lane = tid & 63;
    int wm   = wid >> 1;         // 0..3: 64-row slice
    int wn   = wid & 1;          // 0..1: 160-col (32-h-group x 5 gates) slice
    int half = lane >> 5, l31 = lane & 31;
    int xr   = l31 & 7;          // 3-bit read swizzle key

    int hg = blockIdx.x * 2 + wn;      // 32-h group
    int h  = hg * 32 + l31;            // this lane's h column
    float Bi = bi[h], Bfs = bfs[h], Bft = bft[h], Bo = bo[h], Bc = bc[h];

    f32x16 acc[2][5];
#pragma unroll
    for (int i = 0; i < 2; ++i)
#pragma unroll
        for (int j = 0; j < 5; ++j)
            acc[i][j] = (f32x16)(0.f);

    // ---- staging: row of BK=64 shorts = 8 chunks of 16B.
    // Thread tid -> LDS pos = tid&7 of row (tid>>3) (+64 per round; round
    // stride 64 ≡ 0 mod 8 keeps row&7 invariant). Global chunk = pos ^ (row&7)
    // so LDS[row][pos] holds global chunk pos^(row&7)  (rule #21 both-sides).
    int srow = tid >> 3;                              // 0..63
    int kcS  = ((tid & 7) ^ (srow & 7)) * 8;          // pre-swizzled chunk (shorts)
    const __hip_bfloat16* aBase = A  + (size_t)(m0 + srow) * K_ + kcS;
    const __hip_bfloat16* bBase = WT + (size_t)(n0 + srow) * K_ + kcS;
    int t8 = tid * 8;                                 // linear LDS dst (16B/thr)

#define STG_A(dst, koff)                                                        \
    do {                                                                        \
        _Pragma("unroll")                                                       \
        for (int r_ = 0; r_ < 4; ++r_)                                          \
            GLD16(aBase + (size_t)r_ * 64 * K_ + (koff), (dst) + r_ * 4096 + t8); \
    } while (0)
#define STG_B(dst, koff, rlo, rhi)                                              \
    do {                                                                        \
        _Pragma("unroll")                                                       \
        for (int r_ = (rlo); r_ < (rhi); ++r_)                                  \
            GLD16(bBase + (size_t)r_ * 64 * K_ + (koff), (dst) + r_ * 4096 + t8); \
    } while (0)

    // ---- fragment read offsets: addr(shorts) = row*64 + (g ^ (row&7))*8,
    // g = ks*2 + half; row&7 = xr for all frags (rows are 32-aligned + l31).
    int arow64[2], brow64[5];
#pragma unroll
    for (int i = 0; i < 2; ++i) arow64[i] = (wm * 64 + i * 32 + l31) * 64;
#pragma unroll
    for (int j = 0; j < 5; ++j) brow64[j] = (wn * 160 + j * 32 + l31) * 64;

#define READS(ks_)                                                              \
    int po_ = (((ks_) * 2 + half) ^ xr) * 8;                                    \
    short8 a0 = *(const short8*)(sAc + arow64[0] + po_);                        \
    short8 a1 = *(const short8*)(sAc + arow64[1] + po_);                        \
    short8 b0 = *(const short8*)(sBc + brow64[0] + po_);                        \
    short8 b1 = *(const short8*)(sBc + brow64[1] + po_);                        \
    short8 b2 = *(const short8*)(sBc + brow64[2] + po_);                        \
    short8 b3 = *(const short8*)(sBc + brow64[3] + po_);                        \
    short8 b4 = *(const short8*)(sBc + brow64[4] + po_)

#define MFMAS()                                                                 \
    __builtin_amdgcn_s_setprio(1);                                              \
    acc[0][0] = __builtin_amdgcn_mfma_f32_32x32x16_bf16(a0, b0, acc[0][0], 0, 0, 0); \
    acc[1][0] = __builtin_amdgcn_mfma_f32_32x32x16_bf16(a1, b0, acc[1][0], 0, 0, 0); \
    acc[0][1] = __builtin_amdgcn_mfma_f32_32x32x16_bf16(a0, b1, acc[0][1], 0, 0, 0); \
    acc[1][1] = __builtin_amdgcn_mfma_f32_32x32x16_bf16(a1, b1, acc[1][1], 0, 0, 0); \
    acc[0][2] = __builtin_amdgcn_mfma_f32_32x32x16_bf16(a0, b2, acc[0][2], 0, 0, 0); \
    acc[1][2] = __builtin_amdgcn_mfma_f32_32x32x16_bf16(a1, b2, acc[1][2], 0, 0, 0); \
    acc[0][3] = __builtin_amdgcn_mfma_f32_32x32x16_bf16(a0, b3, acc[0][3], 0, 0, 0); \
    acc[1][3] = __builtin_amdgcn_mfma_f32_32x32x16_bf16(a1, b3, acc[1][3], 0, 0, 0); \
    acc[0][4] = __builtin_amdgcn_mfma_f32_32x32x16_bf16(a0, b4, acc[0][4], 0, 0, 0); \
    acc[1][4] = __builtin_amdgcn_mfma_f32_32x32x16_bf16(a1, b4, acc[1][4], 0, 0, 0); \
    __builtin_amdgcn_s_setprio(0)

#define BAR()   __builtin_amdgcn_s_barrier()
#define LGKM0() asm volatile("s_waitcnt lgkmcnt(0)" ::: "memory")
#define VM0()   asm volatile("s_waitcnt vmcnt(0)" ::: "memory")

    // ---- prologue: stage K-tile 0 ----
    STG_A(sA[0], 0);
    STG_B(sB[0], 0, 0, 5);
    VM0();
    BAR();

    const int nt = K_ / BK_;   // 20
#pragma unroll 2
    for (int t = 0; t < nt; ++t) {
        const unsigned short* sAc = sA[t & 1];
        const unsigned short* sBc = sB[t & 1];
        unsigned short* sAn = sA[(t & 1) ^ 1];
        unsigned short* sBn = sB[(t & 1) ^ 1];
        const bool pf = (t + 1 < nt);
        const int ko = (t + 1) * BK_;

        { // phase 0: A-stage (longest lead, HBM-tolerant) + ks=0
            if (pf) STG_A(sAn, ko);
            READS(0);
            BAR(); LGKM0();
            MFMAS();
            BAR();
        }
        { // phase 1: B-stage rounds 0-2 + ks=1
            if (pf) STG_B(sBn, ko, 0, 3);
            READS(1);
            BAR(); LGKM0();
            MFMAS();
            BAR();
        }
        { // phase 2: B-stage rounds 3-4 + ks=2
            if (pf) STG_B(sBn, ko, 3, 5);
            READS(2);
            BAR(); LGKM0();
            MFMAS();
            BAR();
        }
        { // phase 3: ks=3, then the ONE vmcnt wait per K-step
            READS(3);
            BAR(); LGKM0();
            MFMAS();
            VM0();   // tile t+1 landed (loads are 1-3 phases old)
            BAR();
        }
    }
#undef STG_A
#undef STG_B
#undef READS
#undef MFMAS

    // ---- lane-local LSTM epilogue ----
    // 32x32 C/D layout: col = lane&31 (h), row = (r&3) + 8*(r>>2) + 4*half.
#pragma unroll
    for (int i = 0; i < 2; ++i) {
        int rbase = m0 + wm * 64 + i * 32 + 4 * half;
#pragma unroll
        for (int r = 0; r < 16; ++r) {
            int row = rbase + (r & 3) + 8 * (r >> 2);
            size_t idx = (size_t)row * H_ + h;
            float i_n  = sigf(acc[i][0][r] + Bi);
            float fs_n = sigf(acc[i][1][r] + Bfs);
            float ft_n = sigf(acc[i][2][r] + Bft);
            float o_n  = sigf(acc[i][3][r] + Bo);
            float c_n  = tanhfast(acc[i][4][r] + Bc);
            float ch   = i_n * c_n + ft_n * ct[idx] + fs_n * cs[idx];
            out[idx] = o_n * tanhfast(ch);
            out[(size_t)B_ * H_ + idx] = ch;
        }
    }
}

// ---------------------------------------------------------------------------
// Fallback (ws too small): one block per row, fp32 direct. Slow but correct.
// ---------------------------------------------------------------------------
struct AllW {
    const float* U[5];
    const float* Wt[5];
    const float* Ws[5];
    const float* bias[5];
};

__global__ __launch_bounds__(512) void fallback_kernel(const float* __restrict__ x,
                                                       const float* __restrict__ ht,
                                                       const float* __restrict__ hs,
                                                       const float* __restrict__ ct,
                                                       const float* __restrict__ cs,
                                                       AllW w, float* __restrict__ out) {
    __shared__ float arow[K_];
    int b = blockIdx.x;
    int h = threadIdx.x;
    for (int k = h; k < K_; k += 512) {
        float v;
        if (k < D_)           v = x[b * D_ + k];
        else if (k < D_ + H_) v = ht[b * H_ + k - D_];
        else                  v = hs[b * H_ + k - D_ - H_];
        arow[k] = v;
    }
    __syncthreads();
    float g[5];
    for (int gi = 0; gi < 5; ++gi) {
        float s = w.bias[gi][h];
        const float* U = w.U[gi];
        for (int k = 0; k < D_; ++k) s += arow[k] * U[(size_t)k * H_ + h];
        const float* Wt = w.Wt[gi];
        for (int k = 0; k < H_; ++k) s += arow[D_ + k] * Wt[(size_t)k * H_ + h];
        const float* Ws = w.Ws[gi];
        for (int k = 0; k < H_; ++k) s += arow[D_ + H_ + k] * Ws[(size_t)k * H_ + h];
        g[gi] = s;
    }
    int idx = b * H_ + h;
    float i_n = sigf(g[0]), fs_n = sigf(g[1]), ft_n = sigf(g[2]), o_n = sigf(g[3]);
    float c_n = tanhfast(g[4]);
    float ch  = i_n * c_n + ft_n * ct[idx] + fs_n * cs[idx];
    out[idx] = o_n * tanhfast(ch);
    out[(size_t)B_ * H_ + idx] = ch;
}

// ---------------------------------------------------------------------------
extern "C" void kernel_launch(void* const* d_in, const int* in_sizes, int n_in,
                              void* d_out, int out_size, void* d_ws, size_t ws_size,
                              hipStream_t stream) {
    const float* x  = (const float*)d_in[0];
    const float* ht = (const float*)d_in[1];
    const float* hs = (const float*)d_in[2];
    const float* ct = (const float*)d_in[3];
    const float* cs = (const float*)d_in[4];

    WPtrs wp;
    AllW  aw;
    const float* bias[5];
    for (int g = 0; g < 5; ++g) {
        wp.U[g]  = (const float*)d_in[5 + g * 4 + 0];
        wp.Wt[g] = (const float*)d_in[5 + g * 4 + 1];
        wp.Ws[g] = (const float*)d_in[5 + g * 4 + 2];
        bias[g]  = (const float*)d_in[5 + g * 4 + 3];
        aw.U[g] = wp.U[g]; aw.Wt[g] = wp.Wt[g]; aw.Ws[g] = wp.Ws[g]; aw.bias[g] = bias[g];
    }
    float* out = (float*)d_out;

    size_t szA = (size_t)B_ * K_ * 2;  // 20 MB
    size_t szW = (size_t)N_ * K_ * 2;  // 6.25 MB

    if (ws_size >= szA + szW) {
        __hip_bfloat16* Abf = (__hip_bfloat16*)d_ws;
        __hip_bfloat16* WT  = (__hip_bfloat16*)((char*)d_ws + szA);

        prep_a_kernel<<<5120, 256, 0, stream>>>(x, ht, hs, Abf);
        prep_w_kernel<<<800, 256, 0, stream>>>(wp, WT);
        gemm_fused_kernel<<<dim3(N_ / NT_, B_ / BM_), 512, 0, stream>>>(
            Abf, WT, ct, cs, bias[0], bias[1], bias[2], bias[3], bias[4], out);
    } else {
        fallback_kernel<<<B_, 512, 0, stream>>>(x, ht, hs, ct, cs, aw, out);
    }
}

// Round 6
// 233.136 us; speedup vs baseline: 1.4581x; 1.0351x over previous
//
#include <hip/hip_runtime.h>
#include <hip/hip_bf16.h>
#include <cstdint>
#include <cstddef>

// Problem constants
#define B_  8192
#define D_  256
#define H_  512
#define K_  1280   // D + 2H
#define N_  2560   // 5H
#define NT_ 320    // N-tile: 2 h-groups of (32 h x 5 gates)
#define BM_ 256    // M-tile
#define BK_ 64     // K-step

typedef short short8  __attribute__((ext_vector_type(8)));
typedef float f32x4   __attribute__((ext_vector_type(4)));
typedef float f32x16  __attribute__((ext_vector_type(16)));

__device__ __forceinline__ float sigf(float x)     { return 1.f / (1.f + __expf(-x)); }
__device__ __forceinline__ float tanhfast(float x) { return 1.f - 2.f / (__expf(2.f * x) + 1.f); }

// ---------------------------------------------------------------------------
// prep_w: bf16 WT[n',k], n' = (h>>5)*160 + g*32 + (h&31).  800 blocks.
// (prep_a is GONE this round: the GEMM converts A in-kernel, saving a launch
//  + a 42 MB HBM round-trip of the bf16 A matrix.)
// ---------------------------------------------------------------------------
struct WPtrs {
    const float* U[5];
    const float* Wt[5];
    const float* Ws[5];
};

__global__ void prep_w_kernel(WPtrs p, __hip_bfloat16* __restrict__ WT) {
    __shared__ __hip_bfloat16 tile[64][66];   // 66-pitch: 2-way (free) on read
    int bid2 = blockIdx.x;                 // hblk + 8*(kblk + 20*g)
    int hblk = bid2 & 7;
    int kblk = (bid2 >> 3) % 20;
    int g    = bid2 / 160;
    int k0 = kblk * 64;
    int h0 = hblk * 64;
    const float* src; int kl0;
    if (k0 < 256)      { src = p.U[g];  kl0 = k0; }
    else if (k0 < 768) { src = p.Wt[g]; kl0 = k0 - 256; }
    else               { src = p.Ws[g]; kl0 = k0 - 768; }
    int tid = threadIdx.x;
    int tk = tid >> 6;    // 0..3
    int th = tid & 63;
    for (int r = 0; r < 16; ++r) {
        int kl = r * 4 + tk;
        tile[kl][th] = __float2bfloat16(src[(size_t)(kl0 + kl) * H_ + h0 + th]);
    }
    __syncthreads();
    for (int r = 0; r < 16; ++r) {
        int hl = r * 4 + tk;           // h within tile
        int h  = h0 + hl;
        int np = (h >> 5) * 160 + g * 32 + (h & 31);
        WT[(size_t)np * K_ + k0 + th] = tile[th][hl];
    }
}

// ---------------------------------------------------------------------------
// Fused GEMM + LSTM epilogue — R3 geometry (best measured: 89 us), fence-free
// compiler schedule, with A staged IN-KERNEL from fp32 x/h_t/h_s:
//   - B: global_load_lds w16, global source pre-swizzled (rule #21).
//   - A: reg-staging (fp32 load -> cvt bf16 -> ds_write_b128 at swizzled pos).
//     Each BK=64 k-tile lies in exactly one of {x, h_t, h_s} (256,512 % 64==0).
//     Loads split in two 2-round batches to cap live staging regs at ~16
//     (R4 lesson: acc 160 + frags + staging must stay under 256 VGPR).
// LDS content map (A and B identical): LDS[row][pos] = global chunk
// pos ^ (row&7); frag read pos = (ks*2+half) ^ (row&7).
// A ds_write banks: byte = 128*row + 16*(pos), pos = p ^ (row&7) -> per
// 8-lane row-group the xor spreads the 8 pos over all 32 banks (8-cyc floor).
// Conflicts counter is b128-inherent +4cyc (3 swizzles, same count) - ignore.
// ---------------------------------------------------------------------------
#define GLD16(gp, lp)                                                              \
    __builtin_amdgcn_global_load_lds(                                              \
        (const __attribute__((address_space(1))) unsigned int*)(gp),               \
        (__attribute__((address_space(3))) unsigned int*)(lp), 16, 0, 0)

__global__ __launch_bounds__(512, 2) void gemm_fused_kernel(
    const float* __restrict__ x, const float* __restrict__ ht,
    const float* __restrict__ hs, const __hip_bfloat16* __restrict__ WT,
    const float* __restrict__ ct, const float* __restrict__ cs,
    const float* __restrict__ bi, const float* __restrict__ bfs,
    const float* __restrict__ bft, const float* __restrict__ bo,
    const float* __restrict__ bc, float* __restrict__ out) {
    __shared__ alignas(16) unsigned short sA[2][BM_ * BK_];  // 64 KB
    __shared__ alignas(16) unsigned short sB[2][NT_ * BK_];  // 80 KB

    int tid = threadIdx.x;
    int n0 = blockIdx.x * NT_;   // x = n: all 32 m-blocks of one n-tile share an XCD -> WT L2-hot
    int m0 = blockIdx.y * BM_;
    int wid  = tid >> 6, lane = tid & 63;
    int wm   = wid >> 1;         // 0..3: 64-row slice
    int wn   = wid & 1;          // 0..1: 160-col (32-h-group x 5 gates) slice
    int half = lane >> 5, l31 = lane & 31;
    int xr   = l31 & 7;          // read swizzle key (row&7 of all frag rows)

    int hg = blockIdx.x * 2 + wn;      // 32-h group
    int h  = hg * 32 + l31;            // this lane's h column
    float Bi = bi[h], Bfs = bfs[h], Bft = bft[h], Bo = bo[h], Bc = bc[h];

    f32x16 acc[2][5];
#pragma unroll
    for (int i = 0; i < 2; ++i)
#pragma unroll
        for (int j = 0; j < 5; ++j)
            acc[i][j] = (f32x16)(0.f);

    // ---- staging thread mapping: row srow = tid>>3 (+64/round), chunk p = tid&7.
    int srow = tid >> 3;                 // 0..63
    int pA   = tid & 7;                  // chunk index (8 shorts = 16 B)
    int xk   = srow & 7;                 // write swizzle key (round-invariant)

    // B: global_load_lds, source pre-swizzled, dest linear.
    const __hip_bfloat16* bBase = WT + (size_t)(n0 + srow) * K_ + (pA ^ xk) * 8;
    int t8 = tid * 8;
#define STG_B(dst, koff)                                                          \
    do {                                                                          \
        _Pragma("unroll")                                                         \
        for (int r_ = 0; r_ < 5; ++r_)                                            \
            GLD16(bBase + (size_t)r_ * 64 * K_ + (koff), (dst) + r_ * 4096 + t8); \
    } while (0)

    // A: per-thread fp32 bases into the three sources (plain chunk pA; the
    // swizzle is applied on the WRITE side so ds_write banks spread by xor).
    int rowIdx = m0 + srow;
    const float* xB  = x  + (size_t)rowIdx * D_ + pA * 8;
    const float* htB = ht + (size_t)rowIdx * H_ + pA * 8;
    const float* hsB = hs + (size_t)rowIdx * H_ + pA * 8;
    int aWr = srow * 64 + (pA ^ xk) * 8;     // LDS dst (shorts), +4096/round

#define A_SRC(k0n, aP, aStr)                                                      \
    do {                                                                          \
        if ((k0n) < 256)      { aP = xB + (k0n);        aStr = 64 * D_; }         \
        else if ((k0n) < 768) { aP = htB + ((k0n)-256); aStr = 64 * H_; }         \
        else                  { aP = hsB + ((k0n)-768); aStr = 64 * H_; }         \
    } while (0)

#define A_LOAD2(av, aP, aStr, r0_)                                                \
    do {                                                                          \
        av[0][0] = *(const f32x4*)((aP) + (size_t)((r0_)) * (aStr));              \
        av[0][1] = *(const f32x4*)((aP) + (size_t)((r0_)) * (aStr) + 4);          \
        av[1][0] = *(const f32x4*)((aP) + (size_t)((r0_) + 1) * (aStr));          \
        av[1][1] = *(const f32x4*)((aP) + (size_t)((r0_) + 1) * (aStr) + 4);      \
    } while (0)

#define A_CVTWR(dst, av, r0_)                                                     \
    do {                                                                          \
        _Pragma("unroll")                                                         \
        for (int q_ = 0; q_ < 2; ++q_) {                                          \
            union { short8 s; __hip_bfloat16 hh[8]; } o_;                         \
            o_.hh[0] = __float2bfloat16(av[q_][0][0]);                            \
            o_.hh[1] = __float2bfloat16(av[q_][0][1]);                            \
            o_.hh[2] = __float2bfloat16(av[q_][0][2]);                            \
            o_.hh[3] = __float2bfloat16(av[q_][0][3]);                            \
            o_.hh[4] = __float2bfloat16(av[q_][1][0]);                            \
            o_.hh[5] = __float2bfloat16(av[q_][1][1]);                            \
            o_.hh[6] = __float2bfloat16(av[q_][1][2]);                            \
            o_.hh[7] = __float2bfloat16(av[q_][1][3]);                            \
            *(short8*)((dst) + ((r0_) + q_) * 4096 + aWr) = o_.s;                 \
        }                                                                         \
    } while (0)

    // ---- fragment read offsets: addr(shorts) = row*64 + (g ^ xr)*8.
    int arow64[2], brow64[5];
#pragma unroll
    for (int i = 0; i < 2; ++i) arow64[i] = (wm * 64 + i * 32 + l31) * 64;
#pragma unroll
    for (int j = 0; j < 5; ++j) brow64[j] = (wn * 160 + j * 32 + l31) * 64;

#define KSTEP(ks_)                                                                     \
    do {                                                                               \
        int po_ = (((ks_) * 2 + half) ^ xr) * 8;                                       \
        short8 a0 = *(const short8*)(sAc + arow64[0] + po_);                           \
        short8 a1 = *(const short8*)(sAc + arow64[1] + po_);                           \
        short8 b0 = *(const short8*)(sBc + brow64[0] + po_);                           \
        short8 b1 = *(const short8*)(sBc + brow64[1] + po_);                           \
        short8 b2 = *(const short8*)(sBc + brow64[2] + po_);                           \
        short8 b3 = *(const short8*)(sBc + brow64[3] + po_);                           \
        short8 b4 = *(const short8*)(sBc + brow64[4] + po_);                           \
        __builtin_amdgcn_s_setprio(1);                                                 \
        acc[0][0] = __builtin_amdgcn_mfma_f32_32x32x16_bf16(a0, b0, acc[0][0], 0, 0, 0); \
        acc[1][0] = __builtin_amdgcn_mfma_f32_32x32x16_bf16(a1, b0, acc[1][0], 0, 0, 0); \
        acc[0][1] = __builtin_amdgcn_mfma_f32_32x32x16_bf16(a0, b1, acc[0][1], 0, 0, 0); \
        acc[1][1] = __builtin_amdgcn_mfma_f32_32x32x16_bf16(a1, b1, acc[1][1], 0, 0, 0); \
        acc[0][2] = __builtin_amdgcn_mfma_f32_32x32x16_bf16(a0, b2, acc[0][2], 0, 0, 0); \
        acc[1][2] = __builtin_amdgcn_mfma_f32_32x32x16_bf16(a1, b2, acc[1][2], 0, 0, 0); \
        acc[0][3] = __builtin_amdgcn_mfma_f32_32x32x16_bf16(a0, b3, acc[0][3], 0, 0, 0); \
        acc[1][3] = __builtin_amdgcn_mfma_f32_32x32x16_bf16(a1, b3, acc[1][3], 0, 0, 0); \
        acc[0][4] = __builtin_amdgcn_mfma_f32_32x32x16_bf16(a0, b4, acc[0][4], 0, 0, 0); \
        acc[1][4] = __builtin_amdgcn_mfma_f32_32x32x16_bf16(a1, b4, acc[1][4], 0, 0, 0); \
        __builtin_amdgcn_s_setprio(0);                                                 \
    } while (0)

    // ---- prologue: stage K-tile 0 (k0=0 -> x source) ----
    {
        STG_B(sB[0], 0);
        const float* aP; int aStr;
        A_SRC(0, aP, aStr);
        f32x4 av[2][2];
        A_LOAD2(av, aP, aStr, 0); A_CVTWR(sA[0], av, 0);
        A_LOAD2(av, aP, aStr, 2); A_CVTWR(sA[0], av, 2);
    }
    __syncthreads();

    const int nt = K_ / BK_;   // 20
    for (int t = 0; t < nt; ++t) {
        const int cur = t & 1;
        const unsigned short* sAc = sA[cur];
        const unsigned short* sBc = sB[cur];
        unsigned short* sAn = sA[cur ^ 1];
        unsigned short* sBn = sB[cur ^ 1];
        const bool pf = (t + 1 < nt);
        const int kon = (t + 1) * BK_;

        const float* aP = nullptr; int aStr = 0;
        f32x4 av[2][2];
        if (pf) {
            A_SRC(kon, aP, aStr);
            STG_B(sBn, kon);            // fire-and-forget, lands by barrier
            A_LOAD2(av, aP, aStr, 0);   // batch 1 in flight over ks0/ks1
        }
        KSTEP(0);
        KSTEP(1);
        if (pf) {
            A_CVTWR(sAn, av, 0);        // batch 1 done (had ~2 ks of latency)
            A_LOAD2(av, aP, aStr, 2);   // batch 2 in flight over ks2/ks3
        }
        KSTEP(2);
        KSTEP(3);
        if (pf) A_CVTWR(sAn, av, 2);
        __syncthreads();                // drains GLD16s + ds_writes (one/step)
    }
#undef KSTEP
#undef STG_B
#undef A_SRC
#undef A_LOAD2
#undef A_CVTWR

    // ---- lane-local LSTM epilogue ----
    // 32x32 C/D layout: col = lane&31 (h), row = (r&3) + 8*(r>>2) + 4*half.
#pragma unroll
    for (int i = 0; i < 2; ++i) {
        int rbase = m0 + wm * 64 + i * 32 + 4 * half;
#pragma unroll
        for (int r = 0; r < 16; ++r) {
            int row = rbase + (r & 3) + 8 * (r >> 2);
            size_t idx = (size_t)row * H_ + h;
            float i_n  = sigf(acc[i][0][r] + Bi);
            float fs_n = sigf(acc[i][1][r] + Bfs);
            float ft_n = sigf(acc[i][2][r] + Bft);
            float o_n  = sigf(acc[i][3][r] + Bo);
            float c_n  = tanhfast(acc[i][4][r] + Bc);
            float ch   = i_n * c_n + ft_n * ct[idx] + fs_n * cs[idx];
            out[idx] = o_n * tanhfast(ch);
            out[(size_t)B_ * H_ + idx] = ch;
        }
    }
}

// ---------------------------------------------------------------------------
// Fallback (ws too small): one block per row, fp32 direct. Slow but correct.
// ---------------------------------------------------------------------------
struct AllW {
    const float* U[5];
    const float* Wt[5];
    const float* Ws[5];
    const float* bias[5];
};

__global__ __launch_bounds__(512) void fallback_kernel(const float* __restrict__ x,
                                                       const float* __restrict__ ht,
                                                       const float* __restrict__ hs,
                                                       const float* __restrict__ ct,
                                                       const float* __restrict__ cs,
                                                       AllW w, float* __restrict__ out) {
    __shared__ float arow[K_];
    int b = blockIdx.x;
    int h = threadIdx.x;
    for (int k = h; k < K_; k += 512) {
        float v;
        if (k < D_)           v = x[b * D_ + k];
        else if (k < D_ + H_) v = ht[b * H_ + k - D_];
        else                  v = hs[b * H_ + k - D_ - H_];
        arow[k] = v;
    }
    __syncthreads();
    float g[5];
    for (int gi = 0; gi < 5; ++gi) {
        float s = w.bias[gi][h];
        const float* U = w.U[gi];
        for (int k = 0; k < D_; ++k) s += arow[k] * U[(size_t)k * H_ + h];
        const float* Wt = w.Wt[gi];
        for (int k = 0; k < H_; ++k) s += arow[D_ + k] * Wt[(size_t)k * H_ + h];
        const float* Ws = w.Ws[gi];
        for (int k = 0; k < H_; ++k) s += arow[D_ + H_ + k] * Ws[(size_t)k * H_ + h];
        g[gi] = s;
    }
    int idx = b * H_ + h;
    float i_n = sigf(g[0]), fs_n = sigf(g[1]), ft_n = sigf(g[2]), o_n = sigf(g[3]);
    float c_n = tanhfast(g[4]);
    float ch  = i_n * c_n + ft_n * ct[idx] + fs_n * cs[idx];
    out[idx] = o_n * tanhfast(ch);
    out[(size_t)B_ * H_ + idx] = ch;
}

// ---------------------------------------------------------------------------
extern "C" void kernel_launch(void* const* d_in, const int* in_sizes, int n_in,
                              void* d_out, int out_size, void* d_ws, size_t ws_size,
                              hipStream_t stream) {
    const float* x  = (const float*)d_in[0];
    const float* ht = (const float*)d_in[1];
    const float* hs = (const float*)d_in[2];
    const float* ct = (const float*)d_in[3];
    const float* cs = (const float*)d_in[4];

    WPtrs wp;
    AllW  aw;
    const float* bias[5];
    for (int g = 0; g < 5; ++g) {
        wp.U[g]  = (const float*)d_in[5 + g * 4 + 0];
        wp.Wt[g] = (const float*)d_in[5 + g * 4 + 1];
        wp.Ws[g] = (const float*)d_in[5 + g * 4 + 2];
        bias[g]  = (const float*)d_in[5 + g * 4 + 3];
        aw.U[g] = wp.U[g]; aw.Wt[g] = wp.Wt[g]; aw.Ws[g] = wp.Ws[g]; aw.bias[g] = bias[g];
    }
    float* out = (float*)d_out;

    size_t szW = (size_t)N_ * K_ * 2;  // 6.25 MB

    if (ws_size >= szW) {
        __hip_bfloat16* WT = (__hip_bfloat16*)d_ws;

        prep_w_kernel<<<800, 256, 0, stream>>>(wp, WT);
        gemm_fused_kernel<<<dim3(N_ / NT_, B_ / BM_), 512, 0, stream>>>(
            x, ht, hs, WT, ct, cs, bias[0], bias[1], bias[2], bias[3], bias[4], out);
    } else {
        fallback_kernel<<<B_, 512, 0, stream>>>(x, ht, hs, ct, cs, aw, out);
    }
}

// Round 8
// 229.784 us; speedup vs baseline: 1.4794x; 1.0146x over previous
//
#include <hip/hip_runtime.h>
#include <hip/hip_bf16.h>
#include <cstdint>
#include <cstddef>

// Problem constants
#define B_  8192
#define D_  256
#define H_  512
#define K_  1280   // D + 2H
#define N_  2560   // 5H
#define NT_ 320    // N-tile: 2 h-groups of (32 h x 5 gates)
#define BM_ 256    // M-tile
#define BK_ 64     // K-step

typedef short short8  __attribute__((ext_vector_type(8)));
typedef float f32x4   __attribute__((ext_vector_type(4)));
typedef float f32x16  __attribute__((ext_vector_type(16)));

__device__ __forceinline__ float sigf(float x)     { return 1.f / (1.f + __expf(-x)); }
__device__ __forceinline__ float tanhfast(float x) { return 1.f - 2.f / (__expf(2.f * x) + 1.f); }

// ---------------------------------------------------------------------------
// prep_w: bf16 WT[n',k], n' = (h>>5)*160 + g*32 + (h&31).  800 blocks.
// (prep_a is fused into the GEMM since R6.)
// ---------------------------------------------------------------------------
struct WPtrs {
    const float* U[5];
    const float* Wt[5];
    const float* Ws[5];
};

__global__ void prep_w_kernel(WPtrs p, __hip_bfloat16* __restrict__ WT) {
    __shared__ __hip_bfloat16 tile[64][66];   // 66-pitch: 2-way (free) on read
    int bid2 = blockIdx.x;                 // hblk + 8*(kblk + 20*g)
    int hblk = bid2 & 7;
    int kblk = (bid2 >> 3) % 20;
    int g    = bid2 / 160;
    int k0 = kblk * 64;
    int h0 = hblk * 64;
    const float* src; int kl0;
    if (k0 < 256)      { src = p.U[g];  kl0 = k0; }
    else if (k0 < 768) { src = p.Wt[g]; kl0 = k0 - 256; }
    else               { src = p.Ws[g]; kl0 = k0 - 768; }
    int tid = threadIdx.x;
    int tk = tid >> 6;    // 0..3
    int th = tid & 63;
    for (int r = 0; r < 16; ++r) {
        int kl = r * 4 + tk;
        tile[kl][th] = __float2bfloat16(src[(size_t)(kl0 + kl) * H_ + h0 + th]);
    }
    __syncthreads();
    for (int r = 0; r < 16; ++r) {
        int hl = r * 4 + tk;           // h within tile
        int h  = h0 + hl;
        int np = (h >> 5) * 160 + g * 32 + (h & 31);
        WT[(size_t)np * K_ + k0 + th] = tile[th][hl];
    }
}

// ---------------------------------------------------------------------------
// Fused GEMM + LSTM epilogue — R6 kernel with ONE change: grid x<->y swap.
// (R7 was an infrastructure failure — container died twice, no counters —
//  so this is the SAME experiment resubmitted unchanged.)
//
// R6 post-mortem: FETCH 183.7 MB vs ~82 ideal -> A fetched ~3.4x from HBM.
// Cause: n-on-x grid => XCD k hosted ONLY n-tile k (linear id % 8), so all
// 8 XCDs streamed the FULL 42 MB A through their private 4 MB L2s
// concurrently (zero A reuse in L2; in-loop A loads = L3/HBM latency).
// This round: x = m (32), y = n (8). XCD k now hosts m-stripes {x≡k mod 8}
// for ALL n-tiles: per-XCD A working set = 4 stripes x 1.31 MB = 5.2 MB,
// each stripe reused by its XCD's 8 blocks from L2; A fetched ~once
// chip-wide, A staging loads become L2 hits (covered by the 2-KSTEP lead).
// WT (6.25 MB) now streams per-XCD (L3-hot) - it's 7x smaller than A-fp32.
//
// Everything else identical to R6:
//   - B: global_load_lds w16, source pre-swizzled (rule #21), dest linear.
//   - A: in-kernel fp32->bf16 reg-staging (load -> cvt -> swizzled ds_write),
//     two 2-round batches to cap staging VGPRs (R4 spill lesson).
//   - LDS map: LDS[row][pos] = chunk pos^(row&7); read pos = (ks*2+half)^xr.
//   - Conflicts counter 4.59M = b128-inherent +4cyc/read (3 swizzles, same
//     count) - not actionable.
// ---------------------------------------------------------------------------
#define GLD16(gp, lp)                                                              \
    __builtin_amdgcn_global_load_lds(                                              \
        (const __attribute__((address_space(1))) unsigned int*)(gp),               \
        (__attribute__((address_space(3))) unsigned int*)(lp), 16, 0, 0)

__global__ __launch_bounds__(512, 2) void gemm_fused_kernel(
    const float* __restrict__ x, const float* __restrict__ ht,
    const float* __restrict__ hs, const __hip_bfloat16* __restrict__ WT,
    const float* __restrict__ ct, const float* __restrict__ cs,
    const float* __restrict__ bi, const float* __restrict__ bfs,
    const float* __restrict__ bft, const float* __restrict__ bo,
    const float* __restrict__ bc, float* __restrict__ out) {
    __shared__ alignas(16) unsigned short sA[2][BM_ * BK_];  // 64 KB
    __shared__ alignas(16) unsigned short sB[2][NT_ * BK_];  // 80 KB

    int tid = threadIdx.x;
    int m0 = blockIdx.x * BM_;   // x = m: XCD-mates share A stripes in L2
    int n0 = blockIdx.y * NT_;
    int wid  = tid >> 6, lane = tid & 63;
    int wm   = wid >> 1;         // 0..3: 64-row slice
    int wn   = wid & 1;          // 0..1: 160-col (32-h-group x 5 gates) slice
    int half = lane >> 5, l31 = lane & 31;
    int xr   = l31 & 7;          // read swizzle key (row&7 of all frag rows)

    int hg = blockIdx.y * 2 + wn;      // 32-h group
    int h  = hg * 32 + l31;            // this lane's h column
    float Bi = bi[h], Bfs = bfs[h], Bft = bft[h], Bo = bo[h], Bc = bc[h];

    f32x16 acc[2][5];
#pragma unroll
    for (int i = 0; i < 2; ++i)
#pragma unroll
        for (int j = 0; j < 5; ++j)
            acc[i][j] = (f32x16)(0.f);

    // ---- staging thread mapping: row srow = tid>>3 (+64/round), chunk p = tid&7.
    int srow = tid >> 3;                 // 0..63
    int pA   = tid & 7;                  // chunk index (8 shorts = 16 B)
    int xk   = srow & 7;                 // write swizzle key (round-invariant)

    // B: global_load_lds, source pre-swizzled, dest linear.
    const __hip_bfloat16* bBase = WT + (size_t)(n0 + srow) * K_ + (pA ^ xk) * 8;
    int t8 = tid * 8;
#define STG_B(dst, koff)                                                          \
    do {                                                                          \
        _Pragma("unroll")                                                         \
        for (int r_ = 0; r_ < 5; ++r_)                                            \
            GLD16(bBase + (size_t)r_ * 64 * K_ + (koff), (dst) + r_ * 4096 + t8); \
    } while (0)

    // A: per-thread fp32 bases into the three sources (plain chunk pA; the
    // swizzle is applied on the WRITE side so ds_write banks spread by xor).
    int rowIdx = m0 + srow;
    const float* xB  = x  + (size_t)rowIdx * D_ + pA * 8;
    const float* htB = ht + (size_t)rowIdx * H_ + pA * 8;
    const float* hsB = hs + (size_t)rowIdx * H_ + pA * 8;
    int aWr = srow * 64 + (pA ^ xk) * 8;     // LDS dst (shorts), +4096/round

#define A_SRC(k0n, aP, aStr)                                                      \
    do {                                                                          \
        if ((k0n) < 256)      { aP = xB + (k0n);        aStr = 64 * D_; }         \
        else if ((k0n) < 768) { aP = htB + ((k0n)-256); aStr = 64 * H_; }         \
        else                  { aP = hsB + ((k0n)-768); aStr = 64 * H_; }         \
    } while (0)

#define A_LOAD2(av, aP, aStr, r0_)                                                \
    do {                                                                          \
        av[0][0] = *(const f32x4*)((aP) + (size_t)((r0_)) * (aStr));              \
        av[0][1] = *(const f32x4*)((aP) + (size_t)((r0_)) * (aStr) + 4);          \
        av[1][0] = *(const f32x4*)((aP) + (size_t)((r0_) + 1) * (aStr));          \
        av[1][1] = *(const f32x4*)((aP) + (size_t)((r0_) + 1) * (aStr) + 4);      \
    } while (0)

#define A_CVTWR(dst, av, r0_)                                                     \
    do {                                                                          \
        _Pragma("unroll")                                                         \
        for (int q_ = 0; q_ < 2; ++q_) {                                          \
            union { short8 s; __hip_bfloat16 hh[8]; } o_;                         \
            o_.hh[0] = __float2bfloat16(av[q_][0][0]);                            \
            o_.hh[1] = __float2bfloat16(av[q_][0][1]);                            \
            o_.hh[2] = __float2bfloat16(av[q_][0][2]);                            \
            o_.hh[3] = __float2bfloat16(av[q_][0][3]);                            \
            o_.hh[4] = __float2bfloat16(av[q_][1][0]);                            \
            o_.hh[5] = __float2bfloat16(av[q_][1][1]);                            \
            o_.hh[6] = __float2bfloat16(av[q_][1][2]);                            \
            o_.hh[7] = __float2bfloat16(av[q_][1][3]);                            \
            *(short8*)((dst) + ((r0_) + q_) * 4096 + aWr) = o_.s;                 \
        }                                                                         \
    } while (0)

    // ---- fragment read offsets: addr(shorts) = row*64 + (g ^ xr)*8.
    int arow64[2], brow64[5];
#pragma unroll
    for (int i = 0; i < 2; ++i) arow64[i] = (wm * 64 + i * 32 + l31) * 64;
#pragma unroll
    for (int j = 0; j < 5; ++j) brow64[j] = (wn * 160 + j * 32 + l31) * 64;

#define KSTEP(ks_)                                                                     \
    do {                                                                               \
        int po_ = (((ks_) * 2 + half) ^ xr) * 8;                                       \
        short8 a0 = *(const short8*)(sAc + arow64[0] + po_);                           \
        short8 a1 = *(const short8*)(sAc + arow64[1] + po_);                           \
        short8 b0 = *(const short8*)(sBc + brow64[0] + po_);                           \
        short8 b1 = *(const short8*)(sBc + brow64[1] + po_);                           \
        short8 b2 = *(const short8*)(sBc + brow64[2] + po_);                           \
        short8 b3 = *(const short8*)(sBc + brow64[3] + po_);                           \
        short8 b4 = *(const short8*)(sBc + brow64[4] + po_);                           \
        __builtin_amdgcn_s_setprio(1);                                                 \
        acc[0][0] = __builtin_amdgcn_mfma_f32_32x32x16_bf16(a0, b0, acc[0][0], 0, 0, 0); \
        acc[1][0] = __builtin_amdgcn_mfma_f32_32x32x16_bf16(a1, b0, acc[1][0], 0, 0, 0); \
        acc[0][1] = __builtin_amdgcn_mfma_f32_32x32x16_bf16(a0, b1, acc[0][1], 0, 0, 0); \
        acc[1][1] = __builtin_amdgcn_mfma_f32_32x32x16_bf16(a1, b1, acc[1][1], 0, 0, 0); \
        acc[0][2] = __builtin_amdgcn_mfma_f32_32x32x16_bf16(a0, b2, acc[0][2], 0, 0, 0); \
        acc[1][2] = __builtin_amdgcn_mfma_f32_32x32x16_bf16(a1, b2, acc[1][2], 0, 0, 0); \
        acc[0][3] = __builtin_amdgcn_mfma_f32_32x32x16_bf16(a0, b3, acc[0][3], 0, 0, 0); \
        acc[1][3] = __builtin_amdgcn_mfma_f32_32x32x16_bf16(a1, b3, acc[1][3], 0, 0, 0); \
        acc[0][4] = __builtin_amdgcn_mfma_f32_32x32x16_bf16(a0, b4, acc[0][4], 0, 0, 0); \
        acc[1][4] = __builtin_amdgcn_mfma_f32_32x32x16_bf16(a1, b4, acc[1][4], 0, 0, 0); \
        __builtin_amdgcn_s_setprio(0);                                                 \
    } while (0)

    // ---- prologue: stage K-tile 0 (k0=0 -> x source) ----
    {
        STG_B(sB[0], 0);
        const float* aP; int aStr;
        A_SRC(0, aP, aStr);
        f32x4 av[2][2];
        A_LOAD2(av, aP, aStr, 0); A_CVTWR(sA[0], av, 0);
        A_LOAD2(av, aP, aStr, 2); A_CVTWR(sA[0], av, 2);
    }
    __syncthreads();

    const int nt = K_ / BK_;   // 20
    for (int t = 0; t < nt; ++t) {
        const int cur = t & 1;
        const unsigned short* sAc = sA[cur];
        const unsigned short* sBc = sB[cur];
        unsigned short* sAn = sA[cur ^ 1];
        unsigned short* sBn = sB[cur ^ 1];
        const bool pf = (t + 1 < nt);
        const int kon = (t + 1) * BK_;

        const float* aP = nullptr; int aStr = 0;
        f32x4 av[2][2];
        if (pf) {
            A_SRC(kon, aP, aStr);
            STG_B(sBn, kon);            // fire-and-forget, lands by barrier
            A_LOAD2(av, aP, aStr, 0);   // batch 1 in flight over ks0/ks1
        }
        KSTEP(0);
        KSTEP(1);
        if (pf) {
            A_CVTWR(sAn, av, 0);        // batch 1 done (had ~2 ks of latency)
            A_LOAD2(av, aP, aStr, 2);   // batch 2 in flight over ks2/ks3
        }
        KSTEP(2);
        KSTEP(3);
        if (pf) A_CVTWR(sAn, av, 2);
        __syncthreads();                // drains GLD16s + ds_writes (one/step)
    }
#undef KSTEP
#undef STG_B
#undef A_SRC
#undef A_LOAD2
#undef A_CVTWR

    // ---- lane-local LSTM epilogue ----
    // 32x32 C/D layout: col = lane&31 (h), row = (r&3) + 8*(r>>2) + 4*half.
#pragma unroll
    for (int i = 0; i < 2; ++i) {
        int rbase = m0 + wm * 64 + i * 32 + 4 * half;
#pragma unroll
        for (int r = 0; r < 16; ++r) {
            int row = rbase + (r & 3) + 8 * (r >> 2);
            size_t idx = (size_t)row * H_ + h;
            float i_n  = sigf(acc[i][0][r] + Bi);
            float fs_n = sigf(acc[i][1][r] + Bfs);
            float ft_n = sigf(acc[i][2][r] + Bft);
            float o_n  = sigf(acc[i][3][r] + Bo);
            float c_n  = tanhfast(acc[i][4][r] + Bc);
            float ch   = i_n * c_n + ft_n * ct[idx] + fs_n * cs[idx];
            out[idx] = o_n * tanhfast(ch);
            out[(size_t)B_ * H_ + idx] = ch;
        }
    }
}

// ---------------------------------------------------------------------------
// Fallback (ws too small): one block per row, fp32 direct. Slow but correct.
// ---------------------------------------------------------------------------
struct AllW {
    const float* U[5];
    const float* Wt[5];
    const float* Ws[5];
    const float* bias[5];
};

__global__ __launch_bounds__(512) void fallback_kernel(const float* __restrict__ x,
                                                       const float* __restrict__ ht,
                                                       const float* __restrict__ hs,
                                                       const float* __restrict__ ct,
                                                       const float* __restrict__ cs,
                                                       AllW w, float* __restrict__ out) {
    __shared__ float arow[K_];
    int b = blockIdx.x;
    int h = threadIdx.x;
    for (int k = h; k < K_; k += 512) {
        float v;
        if (k < D_)           v = x[b * D_ + k];
        else if (k < D_ + H_) v = ht[b * H_ + k - D_];
        else                  v = hs[b * H_ + k - D_ - H_];
        arow[k] = v;
    }
    __syncthreads();
    float g[5];
    for (int gi = 0; gi < 5; ++gi) {
        float s = w.bias[gi][h];
        const float* U = w.U[gi];
        for (int k = 0; k < D_; ++k) s += arow[k] * U[(size_t)k * H_ + h];
        const float* Wt = w.Wt[gi];
        for (int k = 0; k < H_; ++k) s += arow[D_ + k] * Wt[(size_t)k * H_ + h];
        const float* Ws = w.Ws[gi];
        for (int k = 0; k < H_; ++k) s += arow[D_ + H_ + k] * Ws[(size_t)k * H_ + h];
        g[gi] = s;
    }
    int idx = b * H_ + h;
    float i_n = sigf(g[0]), fs_n = sigf(g[1]), ft_n = sigf(g[2]), o_n = sigf(g[3]);
    float c_n = tanhfast(g[4]);
    float ch  = i_n * c_n + ft_n * ct[idx] + fs_n * cs[idx];
    out[idx] = o_n * tanhfast(ch);
    out[(size_t)B_ * H_ + idx] = ch;
}

// ---------------------------------------------------------------------------
extern "C" void kernel_launch(void* const* d_in, const int* in_sizes, int n_in,
                              void* d_out, int out_size, void* d_ws, size_t ws_size,
                              hipStream_t stream) {
    const float* x  = (const float*)d_in[0];
    const float* ht = (const float*)d_in[1];
    const float* hs = (const float*)d_in[2];
    const float* ct = (const float*)d_in[3];
    const float* cs = (const float*)d_in[4];

    WPtrs wp;
    AllW  aw;
    const float* bias[5];
    for (int g = 0; g < 5; ++g) {
        wp.U[g]  = (const float*)d_in[5 + g * 4 + 0];
        wp.Wt[g] = (const float*)d_in[5 + g * 4 + 1];
        wp.Ws[g] = (const float*)d_in[5 + g * 4 + 2];
        bias[g]  = (const float*)d_in[5 + g * 4 + 3];
        aw.U[g] = wp.U[g]; aw.Wt[g] = wp.Wt[g]; aw.Ws[g] = wp.Ws[g]; aw.bias[g] = bias[g];
    }
    float* out = (float*)d_out;

    size_t szW = (size_t)N_ * K_ * 2;  // 6.25 MB

    if (ws_size >= szW) {
        __hip_bfloat16* WT = (__hip_bfloat16*)d_ws;

        prep_w_kernel<<<800, 256, 0, stream>>>(wp, WT);
        gemm_fused_kernel<<<dim3(B_ / BM_, N_ / NT_), 512, 0, stream>>>(
            x, ht, hs, WT, ct, cs, bias[0], bias[1], bias[2], bias[3], bias[4], out);
    } else {
        fallback_kernel<<<B_, 512, 0, stream>>>(x, ht, hs, ct, cs, aw, out);
    }
}